// Round 6
// baseline (60.407 us; speedup 1.0000x reference)
//
#include <hip/hip_runtime.h>

#define NB 128
#define NF 512
#define NFRAG 64
#define NFRAMES (NB * NF)
#define TROWS (NF * NFRAG)

typedef unsigned long long u64;

// ---------- cross-lane primitives (R3/R4-proven set ONLY) ----------

template<int CTRL, int ROWM, bool BC>
__device__ __forceinline__ int dppi(int x, int old) {
    return __builtin_amdgcn_update_dpp(old, x, CTRL, ROWM, 0xF, BC);
}
template<int CTRL, int ROWM, bool BC>
__device__ __forceinline__ float dppf(float x, float old) {
    return __int_as_float(dppi<CTRL, ROWM, BC>(__float_as_int(x), __float_as_int(old)));
}
template<int OFS>
__device__ __forceinline__ float swzf(float x) {
    return __int_as_float(__builtin_amdgcn_ds_swizzle(__float_as_int(x), OFS));
}
// xor4 on the VALU pipe: row_shl:4 (0x104) brings lane+4, row_shr:4 (0x114)
// brings lane-4; lanes with (lane&4) need lane-4, others lane+4. Both sources
// are always within the same 16-lane row, so boundary fill never selected.
__device__ __forceinline__ float xor4f(float x, int lane) {
    float up = dppf<0x104, 0xF, true>(x, x);   // row_shl:4 -> lane i gets i+4
    float dn = dppf<0x114, 0xF, true>(x, x);   // row_shr:4 -> lane i gets i-4
    return (lane & 4) ? dn : up;
}

// ---------- 64-lane bitonic sort, QN frames per wave ----------
// xor1 = quad_perm 0xB1, xor2 = quad_perm 0x4E, xor8 = row_ror:8 0x128 (DPP);
// xor4 = DPP pair (above); xor16 = ds_swizzle 0x401F; xor32 = __shfl_xor.

#define QN 4

#define CMPX_Q(K, J) { \
    bool dsc = ((lane & (K)) != 0) != ((lane & (J)) != 0); \
    _Pragma("unroll") for (int q = 0; q < QN; ++q) { \
        bool sw = dsc ? (s[q] < s2[q]) : (s[q] > s2[q]); \
        s[q] = sw ? s2[q] : s[q]; e[q] = sw ? e2[q] : e[q]; } }

#define ST_DPP_Q(K, J, CTRL) { float s2[QN], e2[QN]; \
    _Pragma("unroll") for (int q = 0; q < QN; ++q) { \
        s2[q] = dppf<CTRL, 0xF, true>(s[q], s[q]); \
        e2[q] = dppf<CTRL, 0xF, true>(e[q], e[q]); } \
    CMPX_Q(K, J) }

#define ST_X4_Q(K) { float s2[QN], e2[QN]; \
    _Pragma("unroll") for (int q = 0; q < QN; ++q) { \
        s2[q] = xor4f(s[q], lane); e2[q] = xor4f(e[q], lane); } \
    CMPX_Q(K, 4) }

#define ST_SWZ_Q(K, J, OFS) { float s2[QN], e2[QN]; \
    _Pragma("unroll") for (int q = 0; q < QN; ++q) { \
        s2[q] = swzf<OFS>(s[q]); e2[q] = swzf<OFS>(e[q]); } \
    CMPX_Q(K, J) }

#define ST_SHF_Q(K, J) { float s2[QN], e2[QN]; \
    _Pragma("unroll") for (int q = 0; q < QN; ++q) { \
        s2[q] = __shfl_xor(s[q], J, 64); e2[q] = __shfl_xor(e[q], J, 64); } \
    CMPX_Q(K, J) }

__device__ __forceinline__ void sort64(float (&s)[QN], float (&e)[QN], int lane) {
    ST_DPP_Q(2, 1, 0xB1)
    ST_DPP_Q(4, 2, 0x4E)  ST_DPP_Q(4, 1, 0xB1)
    ST_X4_Q(8) ST_DPP_Q(8, 2, 0x4E) ST_DPP_Q(8, 1, 0xB1)
    ST_DPP_Q(16, 8, 0x128) ST_X4_Q(16) ST_DPP_Q(16, 2, 0x4E) ST_DPP_Q(16, 1, 0xB1)
    ST_SWZ_Q(32, 16, 0x401F) ST_DPP_Q(32, 8, 0x128) ST_X4_Q(32) ST_DPP_Q(32, 2, 0x4E) ST_DPP_Q(32, 1, 0xB1)
    ST_SHF_Q(64, 32)
    ST_SWZ_Q(64, 16, 0x401F) ST_DPP_Q(64, 8, 0x128) ST_X4_Q(64) ST_DPP_Q(64, 2, 0x4E) ST_DPP_Q(64, 1, 0xB1)
}

// ---------- wave64 inclusive scans via DPP ----------

__device__ __forceinline__ void scan_max_q(float (&x)[QN]) {
    const float NI = __int_as_float(0xFF800000u);
#define SMSTEP(CTRL, RM) { _Pragma("unroll") for (int q = 0; q < QN; ++q) \
        x[q] = fmaxf(x[q], dppf<CTRL, RM, false>(x[q], NI)); }
    SMSTEP(0x111, 0xF) SMSTEP(0x112, 0xF) SMSTEP(0x114, 0xF)
    SMSTEP(0x118, 0xF) SMSTEP(0x142, 0xA) SMSTEP(0x143, 0xC)
#undef SMSTEP
}

__device__ __forceinline__ void scan_sum2_q(float (&a)[QN], float (&b)[QN]) {
#define SSSTEP(CTRL, RM) { \
    _Pragma("unroll") for (int q = 0; q < QN; ++q) a[q] += dppf<CTRL, RM, false>(a[q], 0.0f); \
    _Pragma("unroll") for (int q = 0; q < QN; ++q) b[q] += dppf<CTRL, RM, false>(b[q], 0.0f); }
    SSSTEP(0x111, 0xF) SSSTEP(0x112, 0xF) SSSTEP(0x114, 0xF)
    SSSTEP(0x118, 0xF) SSSTEP(0x142, 0xA) SSSTEP(0x143, 0xC)
#undef SSSTEP
}

// ---------- main per-frame kernel: QN frames per wave ----------
template<int MODE>   // 0: rows+counts; 1: direct write at offs; 2: counts only
__global__ __launch_bounds__(256) void frag_kernel(const float2* __restrict__ frags,
                                                   const float* __restrict__ offsets,
                                                   int* __restrict__ counts,
                                                   const int* __restrict__ offs,
                                                   float2* __restrict__ rows,
                                                   float* __restrict__ out) {
    int lane = threadIdx.x & 63;
    int f0 = (blockIdx.x * 4 + (threadIdx.x >> 6)) * QN;

    float s[QN], e[QN];
#pragma unroll
    for (int q = 0; q < QN; ++q) {
        float2 v = frags[(size_t)(f0 + q) * NFRAG + lane];
        s[q] = v.x; e[q] = v.y;
    }
    sort64(s, e, lane);

    float run[QN];
#pragma unroll
    for (int q = 0; q < QN; ++q) run[q] = e[q];
    scan_max_q(run);

    u64 gs[QN];
#pragma unroll
    for (int q = 0; q < QN; ++q) {
        float prev = __shfl_up(run[q], 1, 64);
        bool ng = (lane > 0) && (s[q] > prev);
        gs[q] = __ballot(ng) | 1ull;
    }

    if (MODE == 2) {
        if (lane == 0) {
            int4 c;
            c.x = (int)__popcll(gs[0]); c.y = (int)__popcll(gs[1]);
            c.z = (int)__popcll(gs[2]); c.w = (int)__popcll(gs[3]);
            *(int4*)(counts + f0) = c;
        }
        return;
    }

    u64 le_mask = ((1ull << lane) << 1) - 1ull;   // bits <= lane (lane 63 -> ~0)

    int rank[QN]; u64 r1[QN];
    const float coef = (float)(64.0 / 44100.0);
#pragma unroll
    for (int q = 0; q < QN; ++q) {
        float off = offsets[f0 + q];
        int sc = (int)floorf((s[q] - off) * coef); if (sc < 0) sc = 0;
        int ec = (int)floorf((e[q] - off) * coef); if (ec > 63) ec = 63;
        rank[q] = (sc != 0 && ec != 63) ? 1 : 0;
        r1[q] = __ballot(rank[q] == 1);
    }

    int startL[QN], endL[QN]; u64 span[QN];
#pragma unroll
    for (int q = 0; q < QN; ++q) {
        startL[q] = 63 - __builtin_clzll(gs[q] & le_mask);
        u64 above = gs[q] & ~le_mask;
        endL[q] = above ? (__builtin_ctzll(above) - 1) : 63;
        span[q] = (((1ull << endL[q]) << 1) - 1ull) & ~((1ull << startL[q]) - 1ull);
    }

    bool ismax[QN]; float cnt[QN];
#pragma unroll
    for (int q = 0; q < QN; ++q) {
        int gmax = ((r1[q] & span[q]) != 0ull) ? 1 : 0;
        ismax[q] = (rank[q] == gmax);
        u64 im = __ballot(ismax[q]);
        cnt[q] = (float)__popcll(im & span[q]);   // >= 1 always
    }

    float ps[QN], pe[QN];
#pragma unroll
    for (int q = 0; q < QN; ++q) {
        ps[q] = ismax[q] ? s[q] : 0.0f;
        pe[q] = ismax[q] ? e[q] : 0.0f;
    }
    scan_sum2_q(ps, pe);

#pragma unroll
    for (int q = 0; q < QN; ++q) {
        float bs = __shfl(ps[q], startL[q] - 1, 64);
        float be = __shfl(pe[q], startL[q] - 1, 64);
        if (startL[q] == 0) { bs = 0.0f; be = 0.0f; }
        int gid = (int)__popcll(gs[q] & le_mask) - 1;
        if (lane == endL[q]) {
            float inv = __builtin_amdgcn_rcpf(cnt[q]);   // ~1ulp, threshold 4.5e5
            float2 r;
            r.x = (ps[q] - bs) * inv;
            r.y = (pe[q] - be) * inv;
            int frame = f0 + q;
            if (MODE == 0) {
                rows[(size_t)frame * NFRAG + gid] = r;
            } else {
                int b = frame >> 9;
                ((float2*)out)[(size_t)b * TROWS + offs[frame] + gid] = r;
            }
        }
    }
    if (MODE == 0 && lane == 0) {
        int4 c;
        c.x = (int)__popcll(gs[0]); c.y = (int)__popcll(gs[1]);
        c.z = (int)__popcll(gs[2]); c.w = (int)__popcll(gs[3]);
        *(int4*)(counts + f0) = c;
    }
}

// ---------- per-batch exclusive scan: 1 wave per batch, DPP int scan ----------

__global__ __launch_bounds__(64) void scan_kernel(const int* __restrict__ cnt,
                                                  int* __restrict__ offs,
                                                  int* __restrict__ totals,
                                                  float* __restrict__ out_tail) {
    int b = blockIdx.x, lane = threadIdx.x;
    const int4* p = (const int4*)(cnt + b * NF);
    int4 v0 = p[lane * 2], v1 = p[lane * 2 + 1];
    int l[8] = {v0.x, v0.y, v0.z, v0.w, v1.x, v1.y, v1.z, v1.w};
    int pre[8], sum = 0;
#pragma unroll
    for (int k = 0; k < 8; ++k) { pre[k] = sum; sum += l[k]; }
    int inc = sum;
    inc += dppi<0x111, 0xF, false>(inc, 0);
    inc += dppi<0x112, 0xF, false>(inc, 0);
    inc += dppi<0x114, 0xF, false>(inc, 0);
    inc += dppi<0x118, 0xF, false>(inc, 0);
    inc += dppi<0x142, 0xA, false>(inc, 0);
    inc += dppi<0x143, 0xC, false>(inc, 0);
    int base = inc - sum;                         // exclusive across lanes
    int4 o0 = make_int4(base + pre[0], base + pre[1], base + pre[2], base + pre[3]);
    int4 o1 = make_int4(base + pre[4], base + pre[5], base + pre[6], base + pre[7]);
    int4* op = (int4*)(offs + b * NF);
    op[lane * 2] = o0; op[lane * 2 + 1] = o1;
    int total = __builtin_amdgcn_readlane(inc, 63);
    if (lane == 0) { totals[b] = total; out_tail[b] = (float)total; }
}

// ---------- compaction ----------

__global__ __launch_bounds__(256) void compact_kernel(const float2* __restrict__ rows,
                                                      const int* __restrict__ cnt,
                                                      const int* __restrict__ offs,
                                                      float* __restrict__ out) {
    int lane = threadIdx.x & 63;
    int f0 = (blockIdx.x * 4 + (threadIdx.x >> 6)) * QN;
#pragma unroll
    for (int q = 0; q < QN; ++q) {
        int frame = f0 + q;
        int G = cnt[frame];
        if (lane < G) {
            int b = frame >> 9;
            ((float2*)out)[(size_t)b * TROWS + offs[frame] + lane] =
                rows[(size_t)frame * NFRAG + lane];
        }
    }
}

// ---------- zero padding rows: 4 rows (32B) per thread ----------

__global__ __launch_bounds__(256) void ztail_kernel(const int* __restrict__ totals,
                                                    float* __restrict__ out) {
    int idx = blockIdx.x * 256 + threadIdx.x;
    int b = idx >> 13;                            // / (TROWS/4)
    int r0 = (idx & 8191) * 4;
    int ng = totals[b];
    float* p = out + ((size_t)b * TROWS + r0) * 2;
    if (r0 >= ng) {
        *(float4*)p = make_float4(0.f, 0.f, 0.f, 0.f);
        *(float4*)(p + 4) = make_float4(0.f, 0.f, 0.f, 0.f);
    } else if (r0 + 4 > ng) {
#pragma unroll
        for (int k = 1; k < 4; ++k)
            if (r0 + k >= ng) *(float2*)(p + k * 2) = make_float2(0.f, 0.f);
    }
}

extern "C" void kernel_launch(void* const* d_in, const int* in_sizes, int n_in,
                              void* d_out, int out_size, void* d_ws, size_t ws_size,
                              hipStream_t stream) {
    const float2* frags = (const float2*)d_in[0];   // [B,F,N,2] f32
    const float* offsets = (const float*)d_in[1];   // [B,F] f32
    float* out = (float*)d_out;

    int* counts = (int*)d_ws;
    int* offs = counts + NFRAMES;
    int* totals = offs + NFRAMES;
    float2* rows = (float2*)((char*)d_ws + ((size_t)2 * NFRAMES + NB + 2) * sizeof(int));
    size_t small = ((size_t)2 * NFRAMES + NB + 2) * sizeof(int);
    size_t need = small + (size_t)NFRAMES * NFRAG * sizeof(float2);

    float* tail = out + (size_t)NB * TROWS * 2;

    if (ws_size >= need) {
        frag_kernel<0><<<NFRAMES / 16, 256, 0, stream>>>(frags, offsets, counts, nullptr, rows, nullptr);
        scan_kernel<<<NB, 64, 0, stream>>>(counts, offs, totals, tail);
        compact_kernel<<<NFRAMES / 16, 256, 0, stream>>>(rows, counts, offs, out);
        ztail_kernel<<<NB * TROWS / 4 / 256, 256, 0, stream>>>(totals, out);
    } else {
        frag_kernel<2><<<NFRAMES / 16, 256, 0, stream>>>(frags, offsets, counts, nullptr, nullptr, nullptr);
        scan_kernel<<<NB, 64, 0, stream>>>(counts, offs, totals, tail);
        frag_kernel<1><<<NFRAMES / 16, 256, 0, stream>>>(frags, offsets, counts, offs, nullptr, out);
        ztail_kernel<<<NB * TROWS / 4 / 256, 256, 0, stream>>>(totals, out);
    }
}

// Round 8
// 54.332 us; speedup vs baseline: 1.1118x; 1.1118x over previous
//
#include <hip/hip_runtime.h>

#define NB 128
#define NF 512
#define NFRAG 64
#define NFRAMES (NB * NF)
#define TROWS (NF * NFRAG)

typedef unsigned long long u64;

// ---------- cross-lane primitives (R3/R6-proven set ONLY) ----------

template<int CTRL, int ROWM, bool BC>
__device__ __forceinline__ int dppi(int x, int old) {
    return __builtin_amdgcn_update_dpp(old, x, CTRL, ROWM, 0xF, BC);
}
template<int CTRL, int ROWM, bool BC>
__device__ __forceinline__ float dppf(float x, float old) {
    return __int_as_float(dppi<CTRL, ROWM, BC>(__float_as_int(x), __float_as_int(old)));
}
template<int OFS>
__device__ __forceinline__ float swzf(float x) {
    return __int_as_float(__builtin_amdgcn_ds_swizzle(__float_as_int(x), OFS));
}

// ---------- 64-lane bitonic sort, QN frames per wave ----------
// xor1 = quad_perm 0xB1, xor2 = quad_perm 0x4E, xor8 = row_ror:8 0x128 (DPP);
// xor4 = ds_swizzle 0x101F, xor16 = ds_swizzle 0x401F; xor32 = __shfl_xor.
// Compare-exchange: R6-proven dual-compare form. dsc differs between the two
// lanes of a pair, so the predicate must be symmetric under operand exchange;
// (dsc ? s<s2 : s>s2) is (both lanes agree, no action on ties). The XOR form
// (R7) corrupted payloads on ties -- ties are frequent at ulp~2 magnitudes.

#define QN 4

#define CMPX_Q(K, J) { \
    bool dsc = ((lane & (K)) != 0) != ((lane & (J)) != 0); \
    _Pragma("unroll") for (int q = 0; q < QN; ++q) { \
        bool sw = dsc ? (s[q] < s2[q]) : (s[q] > s2[q]); \
        s[q] = sw ? s2[q] : s[q]; e[q] = sw ? e2[q] : e[q]; } }

#define ST_DPP_Q(K, J, CTRL) { float s2[QN], e2[QN]; \
    _Pragma("unroll") for (int q = 0; q < QN; ++q) { \
        s2[q] = dppf<CTRL, 0xF, true>(s[q], s[q]); \
        e2[q] = dppf<CTRL, 0xF, true>(e[q], e[q]); } \
    CMPX_Q(K, J) }

#define ST_SWZ_Q(K, J, OFS) { float s2[QN], e2[QN]; \
    _Pragma("unroll") for (int q = 0; q < QN; ++q) { \
        s2[q] = swzf<OFS>(s[q]); e2[q] = swzf<OFS>(e[q]); } \
    CMPX_Q(K, J) }

#define ST_SHF_Q(K, J) { float s2[QN], e2[QN]; \
    _Pragma("unroll") for (int q = 0; q < QN; ++q) { \
        s2[q] = __shfl_xor(s[q], J, 64); e2[q] = __shfl_xor(e[q], J, 64); } \
    CMPX_Q(K, J) }

__device__ __forceinline__ void sort64(float (&s)[QN], float (&e)[QN], int lane) {
    ST_DPP_Q(2, 1, 0xB1)
    ST_DPP_Q(4, 2, 0x4E)  ST_DPP_Q(4, 1, 0xB1)
    ST_SWZ_Q(8, 4, 0x101F) ST_DPP_Q(8, 2, 0x4E) ST_DPP_Q(8, 1, 0xB1)
    ST_DPP_Q(16, 8, 0x128) ST_SWZ_Q(16, 4, 0x101F) ST_DPP_Q(16, 2, 0x4E) ST_DPP_Q(16, 1, 0xB1)
    ST_SWZ_Q(32, 16, 0x401F) ST_DPP_Q(32, 8, 0x128) ST_SWZ_Q(32, 4, 0x101F) ST_DPP_Q(32, 2, 0x4E) ST_DPP_Q(32, 1, 0xB1)
    ST_SHF_Q(64, 32)
    ST_SWZ_Q(64, 16, 0x401F) ST_DPP_Q(64, 8, 0x128) ST_SWZ_Q(64, 4, 0x101F) ST_DPP_Q(64, 2, 0x4E) ST_DPP_Q(64, 1, 0xB1)
}

// ---------- wave64 inclusive scans via DPP ----------

__device__ __forceinline__ void scan_max_q(float (&x)[QN]) {
    const float NI = __int_as_float(0xFF800000u);
#define SMSTEP(CTRL, RM) { _Pragma("unroll") for (int q = 0; q < QN; ++q) \
        x[q] = fmaxf(x[q], dppf<CTRL, RM, false>(x[q], NI)); }
    SMSTEP(0x111, 0xF) SMSTEP(0x112, 0xF) SMSTEP(0x114, 0xF)
    SMSTEP(0x118, 0xF) SMSTEP(0x142, 0xA) SMSTEP(0x143, 0xC)
#undef SMSTEP
}

__device__ __forceinline__ void scan_sum2_q(float (&a)[QN], float (&b)[QN]) {
#define SSSTEP(CTRL, RM) { \
    _Pragma("unroll") for (int q = 0; q < QN; ++q) a[q] += dppf<CTRL, RM, false>(a[q], 0.0f); \
    _Pragma("unroll") for (int q = 0; q < QN; ++q) b[q] += dppf<CTRL, RM, false>(b[q], 0.0f); }
    SSSTEP(0x111, 0xF) SSSTEP(0x112, 0xF) SSSTEP(0x114, 0xF)
    SSSTEP(0x118, 0xF) SSSTEP(0x142, 0xA) SSSTEP(0x143, 0xC)
#undef SSSTEP
}

// ---------- main per-frame kernel: QN frames per wave ----------
template<int MODE>   // 0: rows+counts; 1: direct write at offs; 2: counts only
__global__ __launch_bounds__(256) void frag_kernel(const float2* __restrict__ frags,
                                                   const float* __restrict__ offsets,
                                                   int* __restrict__ counts,
                                                   const int* __restrict__ offs,
                                                   float2* __restrict__ rows,
                                                   float* __restrict__ out) {
    int lane = threadIdx.x & 63;
    int f0 = (blockIdx.x * 4 + (threadIdx.x >> 6)) * QN;

    const float2* fp = frags + (size_t)f0 * NFRAG + lane;
    float s[QN], e[QN];
#pragma unroll
    for (int q = 0; q < QN; ++q) {
        float2 v = fp[q * NFRAG];     // 512B apart -> imm-offset loads
        s[q] = v.x; e[q] = v.y;
    }
    sort64(s, e, lane);

    float run[QN];
#pragma unroll
    for (int q = 0; q < QN; ++q) run[q] = e[q];
    scan_max_q(run);

    u64 gs[QN];
#pragma unroll
    for (int q = 0; q < QN; ++q) {
        float prev = __shfl_up(run[q], 1, 64);
        bool ng = (lane > 0) && (s[q] > prev);
        gs[q] = __ballot(ng) | 1ull;
    }

    if (MODE == 2) {
        if (lane == 0) {
            int4 c;
            c.x = (int)__popcll(gs[0]); c.y = (int)__popcll(gs[1]);
            c.z = (int)__popcll(gs[2]); c.w = (int)__popcll(gs[3]);
            *(int4*)(counts + f0) = c;
        }
        return;
    }

    u64 le_mask = ((1ull << lane) << 1) - 1ull;   // bits <= lane (lane 63 -> ~0)

    int rank[QN]; u64 r1[QN];
    const float coef = (float)(64.0 / 44100.0);
#pragma unroll
    for (int q = 0; q < QN; ++q) {
        float off = offsets[f0 + q];
        int sc = (int)floorf((s[q] - off) * coef); if (sc < 0) sc = 0;
        int ec = (int)floorf((e[q] - off) * coef); if (ec > 63) ec = 63;
        rank[q] = (sc != 0 && ec != 63) ? 1 : 0;
        r1[q] = __ballot(rank[q] == 1);
    }

    int startL[QN], endL[QN]; u64 span[QN];
#pragma unroll
    for (int q = 0; q < QN; ++q) {
        startL[q] = 63 - __builtin_clzll(gs[q] & le_mask);
        u64 above = gs[q] & ~le_mask;
        endL[q] = above ? (__builtin_ctzll(above) - 1) : 63;
        span[q] = (((1ull << endL[q]) << 1) - 1ull) & ~((1ull << startL[q]) - 1ull);
    }

    bool ismax[QN]; float cnt[QN];
#pragma unroll
    for (int q = 0; q < QN; ++q) {
        int gmax = ((r1[q] & span[q]) != 0ull) ? 1 : 0;
        ismax[q] = (rank[q] == gmax);
        u64 im = __ballot(ismax[q]);
        cnt[q] = (float)__popcll(im & span[q]);   // >= 1 always
    }

    float xs[QN], xe[QN], ps[QN], pe[QN];
#pragma unroll
    for (int q = 0; q < QN; ++q) {
        xs[q] = ismax[q] ? s[q] : 0.0f;
        xe[q] = ismax[q] ? e[q] : 0.0f;
        ps[q] = xs[q]; pe[q] = xe[q];
    }
    scan_sum2_q(ps, pe);   // inclusive

#pragma unroll
    for (int q = 0; q < QN; ++q) {
        // exclusive prefix read at group start (startL==0 -> reads 0 naturally)
        float bs = __shfl(ps[q] - xs[q], startL[q], 64);
        float be = __shfl(pe[q] - xe[q], startL[q], 64);
        int gid = (int)__popcll(gs[q] & le_mask) - 1;
        if (lane == endL[q]) {
            float inv = __builtin_amdgcn_rcpf(cnt[q]);   // ~1ulp, threshold 4.5e5
            float2 r;
            r.x = (ps[q] - bs) * inv;
            r.y = (pe[q] - be) * inv;
            int frame = f0 + q;
            if (MODE == 0) {
                rows[(size_t)frame * NFRAG + gid] = r;
            } else {
                int b = frame >> 9;
                ((float2*)out)[(size_t)b * TROWS + offs[frame] + gid] = r;
            }
        }
    }
    if (MODE == 0 && lane == 0) {
        int4 c;
        c.x = (int)__popcll(gs[0]); c.y = (int)__popcll(gs[1]);
        c.z = (int)__popcll(gs[2]); c.w = (int)__popcll(gs[3]);
        *(int4*)(counts + f0) = c;
    }
}

// ---------- per-batch exclusive scan: 1 wave per batch, DPP int scan ----------

__global__ __launch_bounds__(64) void scan_kernel(const int* __restrict__ cnt,
                                                  int* __restrict__ offs,
                                                  int* __restrict__ totals,
                                                  float* __restrict__ out_tail) {
    int b = blockIdx.x, lane = threadIdx.x;
    const int4* p = (const int4*)(cnt + b * NF);
    int4 v0 = p[lane * 2], v1 = p[lane * 2 + 1];
    int l[8] = {v0.x, v0.y, v0.z, v0.w, v1.x, v1.y, v1.z, v1.w};
    int pre[8], sum = 0;
#pragma unroll
    for (int k = 0; k < 8; ++k) { pre[k] = sum; sum += l[k]; }
    int inc = sum;
    inc += dppi<0x111, 0xF, false>(inc, 0);
    inc += dppi<0x112, 0xF, false>(inc, 0);
    inc += dppi<0x114, 0xF, false>(inc, 0);
    inc += dppi<0x118, 0xF, false>(inc, 0);
    inc += dppi<0x142, 0xA, false>(inc, 0);
    inc += dppi<0x143, 0xC, false>(inc, 0);
    int base = inc - sum;                         // exclusive across lanes
    int4 o0 = make_int4(base + pre[0], base + pre[1], base + pre[2], base + pre[3]);
    int4 o1 = make_int4(base + pre[4], base + pre[5], base + pre[6], base + pre[7]);
    int4* op = (int4*)(offs + b * NF);
    op[lane * 2] = o0; op[lane * 2 + 1] = o1;
    int total = __builtin_amdgcn_readlane(inc, 63);
    if (lane == 0) { totals[b] = total; out_tail[b] = (float)total; }
}

// ---------- combined tail: zero padding rows + compaction (disjoint regions) ----------

#define ZBLOCKS (NB * TROWS / 4 / 256)   // 4096: each thread zeroes 4 rows
#define CBLOCKS (NFRAMES / 16)           // 4096: 4 waves x QN frames each

__global__ __launch_bounds__(256) void finish_kernel(const float2* __restrict__ rows,
                                                     const int* __restrict__ cnt,
                                                     const int* __restrict__ offs,
                                                     const int* __restrict__ totals,
                                                     float* __restrict__ out) {
    if (blockIdx.x < ZBLOCKS) {
        int idx = blockIdx.x * 256 + threadIdx.x;
        int b = idx >> 13;                        // / (TROWS/4)
        int r0 = (idx & 8191) * 4;
        int ng = totals[b];
        float* p = out + ((size_t)b * TROWS + r0) * 2;
        if (r0 >= ng) {
            *(float4*)p = make_float4(0.f, 0.f, 0.f, 0.f);
            *(float4*)(p + 4) = make_float4(0.f, 0.f, 0.f, 0.f);
        } else if (r0 + 4 > ng) {
#pragma unroll
            for (int k = 1; k < 4; ++k)
                if (r0 + k >= ng) *(float2*)(p + k * 2) = make_float2(0.f, 0.f);
        }
    } else {
        int lane = threadIdx.x & 63;
        int f0 = ((blockIdx.x - ZBLOCKS) * 4 + (threadIdx.x >> 6)) * QN;
#pragma unroll
        for (int q = 0; q < QN; ++q) {
            int frame = f0 + q;
            int G = cnt[frame];
            if (lane < G) {
                int b = frame >> 9;
                ((float2*)out)[(size_t)b * TROWS + offs[frame] + lane] =
                    rows[(size_t)frame * NFRAG + lane];
            }
        }
    }
}

extern "C" void kernel_launch(void* const* d_in, const int* in_sizes, int n_in,
                              void* d_out, int out_size, void* d_ws, size_t ws_size,
                              hipStream_t stream) {
    const float2* frags = (const float2*)d_in[0];   // [B,F,N,2] f32
    const float* offsets = (const float*)d_in[1];   // [B,F] f32
    float* out = (float*)d_out;

    int* counts = (int*)d_ws;
    int* offs = counts + NFRAMES;
    int* totals = offs + NFRAMES;
    float2* rows = (float2*)((char*)d_ws + ((size_t)2 * NFRAMES + NB + 2) * sizeof(int));
    size_t small = ((size_t)2 * NFRAMES + NB + 2) * sizeof(int);
    size_t need = small + (size_t)NFRAMES * NFRAG * sizeof(float2);

    float* tail = out + (size_t)NB * TROWS * 2;

    if (ws_size >= need) {
        frag_kernel<0><<<NFRAMES / 16, 256, 0, stream>>>(frags, offsets, counts, nullptr, rows, nullptr);
        scan_kernel<<<NB, 64, 0, stream>>>(counts, offs, totals, tail);
        finish_kernel<<<ZBLOCKS + CBLOCKS, 256, 0, stream>>>(rows, counts, offs, totals, out);
    } else {
        frag_kernel<2><<<NFRAMES / 16, 256, 0, stream>>>(frags, offsets, counts, nullptr, nullptr, nullptr);
        scan_kernel<<<NB, 64, 0, stream>>>(counts, offs, totals, tail);
        frag_kernel<1><<<NFRAMES / 16, 256, 0, stream>>>(frags, offsets, counts, offs, nullptr, out);
    }
}

// Round 9
// 53.599 us; speedup vs baseline: 1.1270x; 1.0137x over previous
//
#include <hip/hip_runtime.h>

#define NB 128
#define NF 512
#define NFRAG 64
#define NFRAMES (NB * NF)
#define TROWS (NF * NFRAG)

typedef unsigned long long u64;

// ---------- cross-lane primitives (R3/R6/R8-proven set ONLY) ----------

template<int CTRL, int ROWM, bool BC>
__device__ __forceinline__ int dppi(int x, int old) {
    return __builtin_amdgcn_update_dpp(old, x, CTRL, ROWM, 0xF, BC);
}
template<int CTRL, int ROWM, bool BC>
__device__ __forceinline__ float dppf(float x, float old) {
    return __int_as_float(dppi<CTRL, ROWM, BC>(__float_as_int(x), __float_as_int(old)));
}
template<int OFS>
__device__ __forceinline__ float swzf(float x) {
    return __int_as_float(__builtin_amdgcn_ds_swizzle(__float_as_int(x), OFS));
}

// ---------- 64-lane bitonic sort, QN frames per wave ----------
// xor1 = quad_perm 0xB1, xor2 = quad_perm 0x4E, xor8 = row_ror:8 0x128 (DPP);
// xor4 = ds_swizzle 0x101F, xor16 = ds_swizzle 0x401F; xor32 = __shfl_xor.
// Comparator: R6/R8-proven dual-compare form (tie-safe: both lanes of a pair
// evaluate symmetric predicates, no action on ties). Do NOT XOR-fold the two
// compares (R7 failure: duplicates payloads on ties; ties are frequent).

#define QN 4

#define CMPX_Q(K, J) { \
    bool dsc = ((lane & (K)) != 0) != ((lane & (J)) != 0); \
    _Pragma("unroll") for (int q = 0; q < QN; ++q) { \
        bool sw = dsc ? (s[q] < s2[q]) : (s[q] > s2[q]); \
        s[q] = sw ? s2[q] : s[q]; e[q] = sw ? e2[q] : e[q]; } }

#define ST_DPP_Q(K, J, CTRL) { float s2[QN], e2[QN]; \
    _Pragma("unroll") for (int q = 0; q < QN; ++q) { \
        s2[q] = dppf<CTRL, 0xF, true>(s[q], s[q]); \
        e2[q] = dppf<CTRL, 0xF, true>(e[q], e[q]); } \
    CMPX_Q(K, J) }

#define ST_SWZ_Q(K, J, OFS) { float s2[QN], e2[QN]; \
    _Pragma("unroll") for (int q = 0; q < QN; ++q) { \
        s2[q] = swzf<OFS>(s[q]); e2[q] = swzf<OFS>(e[q]); } \
    CMPX_Q(K, J) }

#define ST_SHF_Q(K, J) { float s2[QN], e2[QN]; \
    _Pragma("unroll") for (int q = 0; q < QN; ++q) { \
        s2[q] = __shfl_xor(s[q], J, 64); e2[q] = __shfl_xor(e[q], J, 64); } \
    CMPX_Q(K, J) }

__device__ __forceinline__ void sort64(float (&s)[QN], float (&e)[QN], int lane) {
    ST_DPP_Q(2, 1, 0xB1)
    ST_DPP_Q(4, 2, 0x4E)  ST_DPP_Q(4, 1, 0xB1)
    ST_SWZ_Q(8, 4, 0x101F) ST_DPP_Q(8, 2, 0x4E) ST_DPP_Q(8, 1, 0xB1)
    ST_DPP_Q(16, 8, 0x128) ST_SWZ_Q(16, 4, 0x101F) ST_DPP_Q(16, 2, 0x4E) ST_DPP_Q(16, 1, 0xB1)
    ST_SWZ_Q(32, 16, 0x401F) ST_DPP_Q(32, 8, 0x128) ST_SWZ_Q(32, 4, 0x101F) ST_DPP_Q(32, 2, 0x4E) ST_DPP_Q(32, 1, 0xB1)
    ST_SHF_Q(64, 32)
    ST_SWZ_Q(64, 16, 0x401F) ST_DPP_Q(64, 8, 0x128) ST_SWZ_Q(64, 4, 0x101F) ST_DPP_Q(64, 2, 0x4E) ST_DPP_Q(64, 1, 0xB1)
}

// ---------- wave64 inclusive scans via DPP ----------
// All scanned values are >= 0 (sample coordinates), so 0 is a valid identity
// for BOTH max and sum. Full-row row_shr steps use bound_ctrl=1 (shifted-in
// lanes produce 0 == identity) with old=0, making the old-mov elidable.
// row_bcast steps keep partial row_mask + old=0 (unwritten lanes keep old;
// fmax(x,0)=x and x+=0 are no-ops for them).

__device__ __forceinline__ void scan_max_q(float (&x)[QN]) {
#define SMSTEP(CTRL, RM, BC) { _Pragma("unroll") for (int q = 0; q < QN; ++q) \
        x[q] = fmaxf(x[q], dppf<CTRL, RM, BC>(x[q], 0.0f)); }
    SMSTEP(0x111, 0xF, true) SMSTEP(0x112, 0xF, true) SMSTEP(0x114, 0xF, true)
    SMSTEP(0x118, 0xF, true) SMSTEP(0x142, 0xA, false) SMSTEP(0x143, 0xC, false)
#undef SMSTEP
}

__device__ __forceinline__ void scan_sum2_q(float (&a)[QN], float (&b)[QN]) {
#define SSSTEP(CTRL, RM, BC) { \
    _Pragma("unroll") for (int q = 0; q < QN; ++q) a[q] += dppf<CTRL, RM, BC>(a[q], 0.0f); \
    _Pragma("unroll") for (int q = 0; q < QN; ++q) b[q] += dppf<CTRL, RM, BC>(b[q], 0.0f); }
    SSSTEP(0x111, 0xF, true) SSSTEP(0x112, 0xF, true) SSSTEP(0x114, 0xF, true)
    SSSTEP(0x118, 0xF, true) SSSTEP(0x142, 0xA, false) SSSTEP(0x143, 0xC, false)
#undef SSSTEP
}

// ---------- main per-frame kernel: QN frames per wave ----------
template<int MODE>   // 0: rows+counts; 1: direct write at offs; 2: counts only
__global__ __launch_bounds__(256) void frag_kernel(const float2* __restrict__ frags,
                                                   const float* __restrict__ offsets,
                                                   int* __restrict__ counts,
                                                   const int* __restrict__ offs,
                                                   float2* __restrict__ rows,
                                                   float* __restrict__ out) {
    int lane = threadIdx.x & 63;
    int f0 = (blockIdx.x * 4 + (threadIdx.x >> 6)) * QN;

    const float2* fp = frags + (size_t)f0 * NFRAG + lane;
    float s[QN], e[QN];
#pragma unroll
    for (int q = 0; q < QN; ++q) {
        float2 v = fp[q * NFRAG];     // 512B apart -> imm-offset loads
        s[q] = v.x; e[q] = v.y;
    }
    sort64(s, e, lane);

    float run[QN];
#pragma unroll
    for (int q = 0; q < QN; ++q) run[q] = e[q];
    scan_max_q(run);

    u64 gs[QN];
#pragma unroll
    for (int q = 0; q < QN; ++q) {
        // lane 0: shfl_up clamps to own value, run0 = e0 >= s0 -> ng false;
        // and bit 0 is forced below anyway, so no (lane>0) guard needed.
        float prev = __shfl_up(run[q], 1, 64);
        bool ng = (s[q] > prev);
        gs[q] = __ballot(ng) | 1ull;
    }

    if (MODE == 2) {
        if (lane == 0) {
            int4 c;
            c.x = (int)__popcll(gs[0]); c.y = (int)__popcll(gs[1]);
            c.z = (int)__popcll(gs[2]); c.w = (int)__popcll(gs[3]);
            *(int4*)(counts + f0) = c;
        }
        return;
    }

    u64 le_mask = ((1ull << lane) << 1) - 1ull;   // bits <= lane (lane 63 -> ~0)

    float4 offv = *(const float4*)(offsets + f0);  // f0 % 4 == 0, aligned
    float offa[QN] = {offv.x, offv.y, offv.z, offv.w};

    bool rank[QN]; u64 r1[QN];
    const float coef = (float)(64.0 / 44100.0);
#pragma unroll
    for (int q = 0; q < QN; ++q) {
        float off = offa[q];
        int sc = (int)floorf((s[q] - off) * coef); if (sc < 0) sc = 0;
        int ec = (int)floorf((e[q] - off) * coef); if (ec > 63) ec = 63;
        rank[q] = (sc != 0 && ec != 63);
        r1[q] = __ballot(rank[q]);
    }

    int startL[QN], endL[QN]; u64 span[QN];
#pragma unroll
    for (int q = 0; q < QN; ++q) {
        startL[q] = 63 - __builtin_clzll(gs[q] & le_mask);
        u64 above = gs[q] & ~le_mask;
        endL[q] = above ? (__builtin_ctzll(above) - 1) : 63;
        span[q] = (((1ull << endL[q]) << 1) - 1ull) & ~((1ull << startL[q]) - 1ull);
    }

    bool ismax[QN]; float cnt[QN];
#pragma unroll
    for (int q = 0; q < QN; ++q) {
        bool gmax = (r1[q] & span[q]) != 0ull;
        ismax[q] = (rank[q] == gmax);
        u64 im = __ballot(ismax[q]);
        cnt[q] = (float)__popcll(im & span[q]);   // >= 1 always
    }

    float ps[QN], pe[QN];
#pragma unroll
    for (int q = 0; q < QN; ++q) {
        ps[q] = ismax[q] ? s[q] : 0.0f;
        pe[q] = ismax[q] ? e[q] : 0.0f;
    }
    scan_sum2_q(ps, pe);   // inclusive

#pragma unroll
    for (int q = 0; q < QN; ++q) {
        // exclusive prefix read at group start (startL==0 -> 0 naturally)
        float bs = __shfl(ps[q] - (ismax[q] ? s[q] : 0.0f), startL[q], 64);
        float be = __shfl(pe[q] - (ismax[q] ? e[q] : 0.0f), startL[q], 64);
        int gid = (int)__popcll(gs[q] & le_mask) - 1;
        if (lane == endL[q]) {
            float inv = __builtin_amdgcn_rcpf(cnt[q]);   // ~1ulp, threshold 4.5e5
            float2 r;
            r.x = (ps[q] - bs) * inv;
            r.y = (pe[q] - be) * inv;
            int frame = f0 + q;
            if (MODE == 0) {
                rows[(size_t)frame * NFRAG + gid] = r;
            } else {
                int b = frame >> 9;
                ((float2*)out)[(size_t)b * TROWS + offs[frame] + gid] = r;
            }
        }
    }
    if (MODE == 0 && lane == 0) {
        int4 c;
        c.x = (int)__popcll(gs[0]); c.y = (int)__popcll(gs[1]);
        c.z = (int)__popcll(gs[2]); c.w = (int)__popcll(gs[3]);
        *(int4*)(counts + f0) = c;
    }
}

// ---------- per-batch exclusive scan: 1 wave per batch, DPP int scan ----------

__global__ __launch_bounds__(64) void scan_kernel(const int* __restrict__ cnt,
                                                  int* __restrict__ offs,
                                                  int* __restrict__ totals,
                                                  float* __restrict__ out_tail) {
    int b = blockIdx.x, lane = threadIdx.x;
    const int4* p = (const int4*)(cnt + b * NF);
    int4 v0 = p[lane * 2], v1 = p[lane * 2 + 1];
    int l[8] = {v0.x, v0.y, v0.z, v0.w, v1.x, v1.y, v1.z, v1.w};
    int pre[8], sum = 0;
#pragma unroll
    for (int k = 0; k < 8; ++k) { pre[k] = sum; sum += l[k]; }
    int inc = sum;
    inc += dppi<0x111, 0xF, true>(inc, 0);
    inc += dppi<0x112, 0xF, true>(inc, 0);
    inc += dppi<0x114, 0xF, true>(inc, 0);
    inc += dppi<0x118, 0xF, true>(inc, 0);
    inc += dppi<0x142, 0xA, false>(inc, 0);
    inc += dppi<0x143, 0xC, false>(inc, 0);
    int base = inc - sum;                         // exclusive across lanes
    int4 o0 = make_int4(base + pre[0], base + pre[1], base + pre[2], base + pre[3]);
    int4 o1 = make_int4(base + pre[4], base + pre[5], base + pre[6], base + pre[7]);
    int4* op = (int4*)(offs + b * NF);
    op[lane * 2] = o0; op[lane * 2 + 1] = o1;
    int total = __builtin_amdgcn_readlane(inc, 63);
    if (lane == 0) { totals[b] = total; out_tail[b] = (float)total; }
}

// ---------- combined tail: zero padding rows + compaction (disjoint regions) ----------

#define ZBLOCKS (NB * TROWS / 4 / 256)   // 4096: each thread zeroes 4 rows
#define CBLOCKS (NFRAMES / 16)           // 4096: 4 waves x QN frames each

__global__ __launch_bounds__(256) void finish_kernel(const float2* __restrict__ rows,
                                                     const int* __restrict__ cnt,
                                                     const int* __restrict__ offs,
                                                     const int* __restrict__ totals,
                                                     float* __restrict__ out) {
    if (blockIdx.x < ZBLOCKS) {
        int idx = blockIdx.x * 256 + threadIdx.x;
        int b = idx >> 13;                        // / (TROWS/4)
        int r0 = (idx & 8191) * 4;
        int ng = totals[b];
        float* p = out + ((size_t)b * TROWS + r0) * 2;
        if (r0 >= ng) {
            *(float4*)p = make_float4(0.f, 0.f, 0.f, 0.f);
            *(float4*)(p + 4) = make_float4(0.f, 0.f, 0.f, 0.f);
        } else if (r0 + 4 > ng) {
#pragma unroll
            for (int k = 1; k < 4; ++k)
                if (r0 + k >= ng) *(float2*)(p + k * 2) = make_float2(0.f, 0.f);
        }
    } else {
        int lane = threadIdx.x & 63;
        int f0 = ((blockIdx.x - ZBLOCKS) * 4 + (threadIdx.x >> 6)) * QN;
#pragma unroll
        for (int q = 0; q < QN; ++q) {
            int frame = f0 + q;
            int G = cnt[frame];
            if (lane < G) {
                int b = frame >> 9;
                ((float2*)out)[(size_t)b * TROWS + offs[frame] + lane] =
                    rows[(size_t)frame * NFRAG + lane];
            }
        }
    }
}

extern "C" void kernel_launch(void* const* d_in, const int* in_sizes, int n_in,
                              void* d_out, int out_size, void* d_ws, size_t ws_size,
                              hipStream_t stream) {
    const float2* frags = (const float2*)d_in[0];   // [B,F,N,2] f32
    const float* offsets = (const float*)d_in[1];   // [B,F] f32
    float* out = (float*)d_out;

    int* counts = (int*)d_ws;
    int* offs = counts + NFRAMES;
    int* totals = offs + NFRAMES;
    float2* rows = (float2*)((char*)d_ws + ((size_t)2 * NFRAMES + NB + 2) * sizeof(int));
    size_t small = ((size_t)2 * NFRAMES + NB + 2) * sizeof(int);
    size_t need = small + (size_t)NFRAMES * NFRAG * sizeof(float2);

    float* tail = out + (size_t)NB * TROWS * 2;

    if (ws_size >= need) {
        frag_kernel<0><<<NFRAMES / 16, 256, 0, stream>>>(frags, offsets, counts, nullptr, rows, nullptr);
        scan_kernel<<<NB, 64, 0, stream>>>(counts, offs, totals, tail);
        finish_kernel<<<ZBLOCKS + CBLOCKS, 256, 0, stream>>>(rows, counts, offs, totals, out);
    } else {
        frag_kernel<2><<<NFRAMES / 16, 256, 0, stream>>>(frags, offsets, counts, nullptr, nullptr, nullptr);
        scan_kernel<<<NB, 64, 0, stream>>>(counts, offs, totals, tail);
        finish_kernel<<<ZBLOCKS, 256, 0, stream>>>(nullptr, nullptr, nullptr, totals, out);  // zero-fill only
        frag_kernel<1><<<NFRAMES / 16, 256, 0, stream>>>(frags, offsets, counts, offs, nullptr, out);
    }
}

// Round 10
// 44.213 us; speedup vs baseline: 1.3663x; 1.2123x over previous
//
#include <hip/hip_runtime.h>

#define NB 128
#define NF 512
#define NFRAG 64
#define NFRAMES (NB * NF)
#define TROWS (NF * NFRAG)

typedef unsigned long long u64;
typedef unsigned int u32;

// ---------- cross-lane primitives (R3/R6/R8-proven set ONLY) ----------

template<int CTRL, int ROWM, bool BC>
__device__ __forceinline__ int dppi(int x, int old) {
    return __builtin_amdgcn_update_dpp(old, x, CTRL, ROWM, 0xF, BC);
}
template<int CTRL, int ROWM, bool BC>
__device__ __forceinline__ float dppf(float x, float old) {
    return __int_as_float(dppi<CTRL, ROWM, BC>(__float_as_int(x), __float_as_int(old)));
}
template<int OFS>
__device__ __forceinline__ int swzi(int x) {
    return __builtin_amdgcn_ds_swizzle(x, OFS);
}

// u64 halves <-> key. LLVM treats (u32)(k>>32) / ((u64)h<<32)|l on VGPR pairs
// as subregister ops (free).
__device__ __forceinline__ u32 khi(u64 k) { return (u32)(k >> 32); }
__device__ __forceinline__ u32 klo(u64 k) { return (u32)k; }
__device__ __forceinline__ u64 mkk(u32 h, u32 l) { return ((u64)h << 32) | l; }

// ---------- 64-lane bitonic sort on u64 keys (s<<32|e), QN frames/wave ----------
// Key order: unsigned u64 == lexicographic (s,e) on nonneg floats. Total order
// on elements => XOR-fold comparator is tie-safe (equal keys = identical
// elements; swap/dup is a no-op). R7's tie bug does NOT apply here.
// xor1 = quad_perm 0xB1, xor2 = quad_perm 0x4E, xor8 = row_ror:8 0x128 (DPP);
// xor4 = ds_swizzle 0x101F, xor16 = ds_swizzle 0x401F; xor32 = __shfl_xor.

#define QN 4

#define CMPX_Q(K, J) { \
    bool dsc = ((lane & (K)) != 0) != ((lane & (J)) != 0); \
    _Pragma("unroll") for (int q = 0; q < QN; ++q) { \
        bool sw = dsc != (k2[q] < k[q]); \
        k[q] = sw ? k2[q] : k[q]; } }

#define ST_DPP_Q(K, J, CTRL) { u64 k2[QN]; \
    _Pragma("unroll") for (int q = 0; q < QN; ++q) { \
        u32 h = (u32)dppi<CTRL, 0xF, true>((int)khi(k[q]), (int)khi(k[q])); \
        u32 l = (u32)dppi<CTRL, 0xF, true>((int)klo(k[q]), (int)klo(k[q])); \
        k2[q] = mkk(h, l); } \
    CMPX_Q(K, J) }

#define ST_SWZ_Q(K, J, OFS) { u64 k2[QN]; \
    _Pragma("unroll") for (int q = 0; q < QN; ++q) { \
        u32 h = (u32)swzi<OFS>((int)khi(k[q])); \
        u32 l = (u32)swzi<OFS>((int)klo(k[q])); \
        k2[q] = mkk(h, l); } \
    CMPX_Q(K, J) }

#define ST_SHF_Q(K, J) { u64 k2[QN]; \
    _Pragma("unroll") for (int q = 0; q < QN; ++q) { \
        u32 h = (u32)__shfl_xor((int)khi(k[q]), J, 64); \
        u32 l = (u32)__shfl_xor((int)klo(k[q]), J, 64); \
        k2[q] = mkk(h, l); } \
    CMPX_Q(K, J) }

__device__ __forceinline__ void sort64(u64 (&k)[QN], int lane) {
    ST_DPP_Q(2, 1, 0xB1)
    ST_DPP_Q(4, 2, 0x4E)  ST_DPP_Q(4, 1, 0xB1)
    ST_SWZ_Q(8, 4, 0x101F) ST_DPP_Q(8, 2, 0x4E) ST_DPP_Q(8, 1, 0xB1)
    ST_DPP_Q(16, 8, 0x128) ST_SWZ_Q(16, 4, 0x101F) ST_DPP_Q(16, 2, 0x4E) ST_DPP_Q(16, 1, 0xB1)
    ST_SWZ_Q(32, 16, 0x401F) ST_DPP_Q(32, 8, 0x128) ST_SWZ_Q(32, 4, 0x101F) ST_DPP_Q(32, 2, 0x4E) ST_DPP_Q(32, 1, 0xB1)
    ST_SHF_Q(64, 32)
    ST_SWZ_Q(64, 16, 0x401F) ST_DPP_Q(64, 8, 0x128) ST_SWZ_Q(64, 4, 0x101F) ST_DPP_Q(64, 2, 0x4E) ST_DPP_Q(64, 1, 0xB1)
}

// ---------- wave64 inclusive scans via DPP (0 is identity: all values >= 0) ----------

__device__ __forceinline__ void scan_max_q(float (&x)[QN]) {
#define SMSTEP(CTRL, RM, BC) { _Pragma("unroll") for (int q = 0; q < QN; ++q) \
        x[q] = fmaxf(x[q], dppf<CTRL, RM, BC>(x[q], 0.0f)); }
    SMSTEP(0x111, 0xF, true) SMSTEP(0x112, 0xF, true) SMSTEP(0x114, 0xF, true)
    SMSTEP(0x118, 0xF, true) SMSTEP(0x142, 0xA, false) SMSTEP(0x143, 0xC, false)
#undef SMSTEP
}

__device__ __forceinline__ void scan_sum2_q(float (&a)[QN], float (&b)[QN]) {
#define SSSTEP(CTRL, RM, BC) { \
    _Pragma("unroll") for (int q = 0; q < QN; ++q) a[q] += dppf<CTRL, RM, BC>(a[q], 0.0f); \
    _Pragma("unroll") for (int q = 0; q < QN; ++q) b[q] += dppf<CTRL, RM, BC>(b[q], 0.0f); }
    SSSTEP(0x111, 0xF, true) SSSTEP(0x112, 0xF, true) SSSTEP(0x114, 0xF, true)
    SSSTEP(0x118, 0xF, true) SSSTEP(0x142, 0xA, false) SSSTEP(0x143, 0xC, false)
#undef SSSTEP
}

// ---------- main per-frame kernel: QN frames per wave ----------
template<int MODE>   // 0: rows+counts; 1: direct write at offs; 2: counts only
__global__ __launch_bounds__(256) void frag_kernel(const float2* __restrict__ frags,
                                                   const float* __restrict__ offsets,
                                                   int* __restrict__ counts,
                                                   const int* __restrict__ offs,
                                                   float2* __restrict__ rows,
                                                   float* __restrict__ out) {
    int lane = threadIdx.x & 63;
    int f0 = (blockIdx.x * 4 + (threadIdx.x >> 6)) * QN;

    const float2* fp = frags + (size_t)f0 * NFRAG + lane;
    u64 k[QN];
#pragma unroll
    for (int q = 0; q < QN; ++q) {
        float2 v = fp[q * NFRAG];     // 512B apart -> imm-offset loads
        k[q] = mkk(__float_as_uint(v.x), __float_as_uint(v.y));
    }
    sort64(k, lane);

    float s[QN], e[QN];
#pragma unroll
    for (int q = 0; q < QN; ++q) {
        s[q] = __uint_as_float(khi(k[q]));
        e[q] = __uint_as_float(klo(k[q]));
    }

    float run[QN];
#pragma unroll
    for (int q = 0; q < QN; ++q) run[q] = e[q];
    scan_max_q(run);

    u64 gs[QN];
#pragma unroll
    for (int q = 0; q < QN; ++q) {
        // lane 0: shfl_up clamps to own value, run0 = e0 >= s0 -> ng false;
        // bit 0 forced below anyway.
        float prev = __shfl_up(run[q], 1, 64);
        bool ng = (s[q] > prev);
        gs[q] = __ballot(ng) | 1ull;
    }

    if (MODE == 2) {
        if (lane == 0) {
            int4 c;
            c.x = (int)__popcll(gs[0]); c.y = (int)__popcll(gs[1]);
            c.z = (int)__popcll(gs[2]); c.w = (int)__popcll(gs[3]);
            *(int4*)(counts + f0) = c;
        }
        return;
    }

    u64 le_mask = ((1ull << lane) << 1) - 1ull;   // bits <= lane (lane 63 -> ~0)

    float4 offv = *(const float4*)(offsets + f0);  // f0 % 4 == 0, aligned
    float offa[QN] = {offv.x, offv.y, offv.z, offv.w};

    bool rank[QN]; u64 r1[QN];
    const float coef = (float)(64.0 / 44100.0);
#pragma unroll
    for (int q = 0; q < QN; ++q) {
        float off = offa[q];
        int sc = (int)floorf((s[q] - off) * coef); if (sc < 0) sc = 0;
        int ec = (int)floorf((e[q] - off) * coef); if (ec > 63) ec = 63;
        rank[q] = (sc != 0 && ec != 63);
        r1[q] = __ballot(rank[q]);
    }

    int startL[QN], endL[QN]; u64 span[QN];
#pragma unroll
    for (int q = 0; q < QN; ++q) {
        startL[q] = 63 - __builtin_clzll(gs[q] & le_mask);
        u64 above = gs[q] & ~le_mask;
        endL[q] = above ? (__builtin_ctzll(above) - 1) : 63;
        span[q] = (((1ull << endL[q]) << 1) - 1ull) & ~((1ull << startL[q]) - 1ull);
    }

    bool ismax[QN]; float cnt[QN];
#pragma unroll
    for (int q = 0; q < QN; ++q) {
        bool gmax = (r1[q] & span[q]) != 0ull;
        ismax[q] = (rank[q] == gmax);
        u64 im = __ballot(ismax[q]);
        cnt[q] = (float)__popcll(im & span[q]);   // >= 1 always
    }

    float ps[QN], pe[QN];
#pragma unroll
    for (int q = 0; q < QN; ++q) {
        ps[q] = ismax[q] ? s[q] : 0.0f;
        pe[q] = ismax[q] ? e[q] : 0.0f;
    }
    scan_sum2_q(ps, pe);   // inclusive

#pragma unroll
    for (int q = 0; q < QN; ++q) {
        // exclusive prefix read at group start (startL==0 -> 0 naturally)
        float bs = __shfl(ps[q] - (ismax[q] ? s[q] : 0.0f), startL[q], 64);
        float be = __shfl(pe[q] - (ismax[q] ? e[q] : 0.0f), startL[q], 64);
        int gid = (int)__popcll(gs[q] & le_mask) - 1;
        if (lane == endL[q]) {
            float inv = __builtin_amdgcn_rcpf(cnt[q]);   // ~1ulp, threshold 4.5e5
            float2 r;
            r.x = (ps[q] - bs) * inv;
            r.y = (pe[q] - be) * inv;
            int frame = f0 + q;
            if (MODE == 0) {
                rows[(size_t)frame * NFRAG + gid] = r;
            } else {
                int b = frame >> 9;
                ((float2*)out)[(size_t)b * TROWS + offs[frame] + gid] = r;
            }
        }
    }
    if (MODE == 0 && lane == 0) {
        int4 c;
        c.x = (int)__popcll(gs[0]); c.y = (int)__popcll(gs[1]);
        c.z = (int)__popcll(gs[2]); c.w = (int)__popcll(gs[3]);
        *(int4*)(counts + f0) = c;
    }
}

// ---------- per-batch exclusive scan: 1 wave per batch, DPP int scan ----------

__global__ __launch_bounds__(64) void scan_kernel(const int* __restrict__ cnt,
                                                  int* __restrict__ offs,
                                                  int* __restrict__ totals,
                                                  float* __restrict__ out_tail) {
    int b = blockIdx.x, lane = threadIdx.x;
    const int4* p = (const int4*)(cnt + b * NF);
    int4 v0 = p[lane * 2], v1 = p[lane * 2 + 1];
    int l[8] = {v0.x, v0.y, v0.z, v0.w, v1.x, v1.y, v1.z, v1.w};
    int pre[8], sum = 0;
#pragma unroll
    for (int kk = 0; kk < 8; ++kk) { pre[kk] = sum; sum += l[kk]; }
    int inc = sum;
    inc += dppi<0x111, 0xF, true>(inc, 0);
    inc += dppi<0x112, 0xF, true>(inc, 0);
    inc += dppi<0x114, 0xF, true>(inc, 0);
    inc += dppi<0x118, 0xF, true>(inc, 0);
    inc += dppi<0x142, 0xA, false>(inc, 0);
    inc += dppi<0x143, 0xC, false>(inc, 0);
    int base = inc - sum;                         // exclusive across lanes
    int4 o0 = make_int4(base + pre[0], base + pre[1], base + pre[2], base + pre[3]);
    int4 o1 = make_int4(base + pre[4], base + pre[5], base + pre[6], base + pre[7]);
    int4* op = (int4*)(offs + b * NF);
    op[lane * 2] = o0; op[lane * 2 + 1] = o1;
    int total = __builtin_amdgcn_readlane(inc, 63);
    if (lane == 0) { totals[b] = total; out_tail[b] = (float)total; }
}

// ---------- combined tail: zero padding rows + compaction (disjoint regions) ----------

#define ZBLOCKS (NB * TROWS / 4 / 256)   // 4096: each thread zeroes 4 rows
#define CBLOCKS (NFRAMES / 16)           // 4096: 4 waves x QN frames each

__global__ __launch_bounds__(256) void finish_kernel(const float2* __restrict__ rows,
                                                     const int* __restrict__ cnt,
                                                     const int* __restrict__ offs,
                                                     const int* __restrict__ totals,
                                                     float* __restrict__ out) {
    if (blockIdx.x < ZBLOCKS) {
        int idx = blockIdx.x * 256 + threadIdx.x;
        int b = idx >> 13;                        // / (TROWS/4)
        int r0 = (idx & 8191) * 4;
        int ng = totals[b];
        float* p = out + ((size_t)b * TROWS + r0) * 2;
        if (r0 >= ng) {
            *(float4*)p = make_float4(0.f, 0.f, 0.f, 0.f);
            *(float4*)(p + 4) = make_float4(0.f, 0.f, 0.f, 0.f);
        } else if (r0 + 4 > ng) {
#pragma unroll
            for (int kk = 1; kk < 4; ++kk)
                if (r0 + kk >= ng) *(float2*)(p + kk * 2) = make_float2(0.f, 0.f);
        }
    } else {
        int lane = threadIdx.x & 63;
        int f0 = ((blockIdx.x - ZBLOCKS) * 4 + (threadIdx.x >> 6)) * QN;
#pragma unroll
        for (int q = 0; q < QN; ++q) {
            int frame = f0 + q;
            int G = cnt[frame];
            if (lane < G) {
                int b = frame >> 9;
                ((float2*)out)[(size_t)b * TROWS + offs[frame] + lane] =
                    rows[(size_t)frame * NFRAG + lane];
            }
        }
    }
}

extern "C" void kernel_launch(void* const* d_in, const int* in_sizes, int n_in,
                              void* d_out, int out_size, void* d_ws, size_t ws_size,
                              hipStream_t stream) {
    const float2* frags = (const float2*)d_in[0];   // [B,F,N,2] f32
    const float* offsets = (const float*)d_in[1];   // [B,F] f32
    float* out = (float*)d_out;

    int* counts = (int*)d_ws;
    int* offs = counts + NFRAMES;
    int* totals = offs + NFRAMES;
    float2* rows = (float2*)((char*)d_ws + ((size_t)2 * NFRAMES + NB + 2) * sizeof(int));
    size_t small = ((size_t)2 * NFRAMES + NB + 2) * sizeof(int);
    size_t need = small + (size_t)NFRAMES * NFRAG * sizeof(float2);

    float* tail = out + (size_t)NB * TROWS * 2;

    if (ws_size >= need) {
        frag_kernel<0><<<NFRAMES / 16, 256, 0, stream>>>(frags, offsets, counts, nullptr, rows, nullptr);
        scan_kernel<<<NB, 64, 0, stream>>>(counts, offs, totals, tail);
        finish_kernel<<<ZBLOCKS + CBLOCKS, 256, 0, stream>>>(rows, counts, offs, totals, out);
    } else {
        frag_kernel<2><<<NFRAMES / 16, 256, 0, stream>>>(frags, offsets, counts, nullptr, nullptr, nullptr);
        scan_kernel<<<NB, 64, 0, stream>>>(counts, offs, totals, tail);
        finish_kernel<<<ZBLOCKS, 256, 0, stream>>>(nullptr, nullptr, nullptr, totals, out);  // zero-fill only
        frag_kernel<1><<<NFRAMES / 16, 256, 0, stream>>>(frags, offsets, counts, offs, nullptr, out);
    }
}

// Round 11
// 40.388 us; speedup vs baseline: 1.4957x; 1.0947x over previous
//
#include <hip/hip_runtime.h>

#define NB 128
#define NF 512
#define NFRAG 64
#define NFRAMES (NB * NF)
#define TROWS (NF * NFRAG)

typedef unsigned long long u64;
typedef unsigned int u32;

// ---------- cross-lane primitives (R3/R6/R8/R10-proven set ONLY) ----------

template<int CTRL, int ROWM, bool BC>
__device__ __forceinline__ int dppi(int x, int old) {
    return __builtin_amdgcn_update_dpp(old, x, CTRL, ROWM, 0xF, BC);
}
template<int CTRL, int ROWM, bool BC>
__device__ __forceinline__ float dppf(float x, float old) {
    return __int_as_float(dppi<CTRL, ROWM, BC>(__float_as_int(x), __float_as_int(old)));
}
template<int OFS>
__device__ __forceinline__ int swzi(int x) {
    return __builtin_amdgcn_ds_swizzle(x, OFS);
}

__device__ __forceinline__ u32 khi(u64 k) { return (u32)(k >> 32); }
__device__ __forceinline__ u32 klo(u64 k) { return (u32)k; }
__device__ __forceinline__ u64 mkk(u32 h, u32 l) { return ((u64)h << 32) | l; }

// ---------- 64-lane bitonic sort on u64 keys (s<<32|e), QN frames/wave ----------
// u64 unsigned order == lexicographic (s,e) on nonneg floats; total order makes
// the XOR-fold comparator tie-safe (equal keys = identical elements).
// xor1 = quad_perm 0xB1, xor2 = quad_perm 0x4E, xor8 = row_ror:8 0x128 (DPP);
// xor4 = ds_swizzle 0x101F, xor16 = ds_swizzle 0x401F; xor32 = __shfl_xor.

#define QN 4

#define CMPX_Q(K, J) { \
    bool dsc = ((lane & (K)) != 0) != ((lane & (J)) != 0); \
    _Pragma("unroll") for (int q = 0; q < QN; ++q) { \
        bool sw = dsc != (k2[q] < k[q]); \
        k[q] = sw ? k2[q] : k[q]; } }

#define ST_DPP_Q(K, J, CTRL) { u64 k2[QN]; \
    _Pragma("unroll") for (int q = 0; q < QN; ++q) { \
        u32 h = (u32)dppi<CTRL, 0xF, true>((int)khi(k[q]), (int)khi(k[q])); \
        u32 l = (u32)dppi<CTRL, 0xF, true>((int)klo(k[q]), (int)klo(k[q])); \
        k2[q] = mkk(h, l); } \
    CMPX_Q(K, J) }

#define ST_SWZ_Q(K, J, OFS) { u64 k2[QN]; \
    _Pragma("unroll") for (int q = 0; q < QN; ++q) { \
        u32 h = (u32)swzi<OFS>((int)khi(k[q])); \
        u32 l = (u32)swzi<OFS>((int)klo(k[q])); \
        k2[q] = mkk(h, l); } \
    CMPX_Q(K, J) }

#define ST_SHF_Q(K, J) { u64 k2[QN]; \
    _Pragma("unroll") for (int q = 0; q < QN; ++q) { \
        u32 h = (u32)__shfl_xor((int)khi(k[q]), J, 64); \
        u32 l = (u32)__shfl_xor((int)klo(k[q]), J, 64); \
        k2[q] = mkk(h, l); } \
    CMPX_Q(K, J) }

__device__ __forceinline__ void sort64(u64 (&k)[QN], int lane) {
    ST_DPP_Q(2, 1, 0xB1)
    ST_DPP_Q(4, 2, 0x4E)  ST_DPP_Q(4, 1, 0xB1)
    ST_SWZ_Q(8, 4, 0x101F) ST_DPP_Q(8, 2, 0x4E) ST_DPP_Q(8, 1, 0xB1)
    ST_DPP_Q(16, 8, 0x128) ST_SWZ_Q(16, 4, 0x101F) ST_DPP_Q(16, 2, 0x4E) ST_DPP_Q(16, 1, 0xB1)
    ST_SWZ_Q(32, 16, 0x401F) ST_DPP_Q(32, 8, 0x128) ST_SWZ_Q(32, 4, 0x101F) ST_DPP_Q(32, 2, 0x4E) ST_DPP_Q(32, 1, 0xB1)
    ST_SHF_Q(64, 32)
    ST_SWZ_Q(64, 16, 0x401F) ST_DPP_Q(64, 8, 0x128) ST_SWZ_Q(64, 4, 0x101F) ST_DPP_Q(64, 2, 0x4E) ST_DPP_Q(64, 1, 0xB1)
}

// ---------- wave64 inclusive scans via DPP (0 is identity: all values >= 0) ----------

__device__ __forceinline__ void scan_max_q(float (&x)[QN]) {
#define SMSTEP(CTRL, RM, BC) { _Pragma("unroll") for (int q = 0; q < QN; ++q) \
        x[q] = fmaxf(x[q], dppf<CTRL, RM, BC>(x[q], 0.0f)); }
    SMSTEP(0x111, 0xF, true) SMSTEP(0x112, 0xF, true) SMSTEP(0x114, 0xF, true)
    SMSTEP(0x118, 0xF, true) SMSTEP(0x142, 0xA, false) SMSTEP(0x143, 0xC, false)
#undef SMSTEP
}

__device__ __forceinline__ void scan_sum2_q(float (&a)[QN], float (&b)[QN]) {
#define SSSTEP(CTRL, RM, BC) { \
    _Pragma("unroll") for (int q = 0; q < QN; ++q) a[q] += dppf<CTRL, RM, BC>(a[q], 0.0f); \
    _Pragma("unroll") for (int q = 0; q < QN; ++q) b[q] += dppf<CTRL, RM, BC>(b[q], 0.0f); }
    SSSTEP(0x111, 0xF, true) SSSTEP(0x112, 0xF, true) SSSTEP(0x114, 0xF, true)
    SSSTEP(0x118, 0xF, true) SSSTEP(0x142, 0xA, false) SSSTEP(0x143, 0xC, false)
#undef SSSTEP
}

// ---------- main per-frame kernel: QN frames per wave ----------
template<int MODE>   // 0: rows+counts; 1: direct write at offs; 2: counts only
__global__ __launch_bounds__(256) void frag_kernel(const float2* __restrict__ frags,
                                                   const float* __restrict__ offsets,
                                                   int* __restrict__ counts,
                                                   const int* __restrict__ offs,
                                                   float2* __restrict__ rows,
                                                   float* __restrict__ out) {
    int lane = threadIdx.x & 63;
    int f0 = (blockIdx.x * 4 + (threadIdx.x >> 6)) * QN;

    const float2* fp = frags + (size_t)f0 * NFRAG + lane;
    u64 k[QN];
#pragma unroll
    for (int q = 0; q < QN; ++q) {
        float2 v = fp[q * NFRAG];     // 512B apart -> imm-offset loads
        k[q] = mkk(__float_as_uint(v.x), __float_as_uint(v.y));
    }
    sort64(k, lane);

    float s[QN], e[QN];
#pragma unroll
    for (int q = 0; q < QN; ++q) {
        s[q] = __uint_as_float(khi(k[q]));
        e[q] = __uint_as_float(klo(k[q]));
    }

    float run[QN];
#pragma unroll
    for (int q = 0; q < QN; ++q) run[q] = e[q];
    scan_max_q(run);

    u64 gs[QN];
#pragma unroll
    for (int q = 0; q < QN; ++q) {
        // lane 0: shfl_up clamps to own value, run0 = e0 >= s0 -> ng false;
        // bit 0 forced below anyway.
        float prev = __shfl_up(run[q], 1, 64);
        bool ng = (s[q] > prev);
        gs[q] = __ballot(ng) | 1ull;
    }

    if (MODE == 2) {
        if (lane == 0) {
            int4 c;
            c.x = (int)__popcll(gs[0]); c.y = (int)__popcll(gs[1]);
            c.z = (int)__popcll(gs[2]); c.w = (int)__popcll(gs[3]);
            *(int4*)(counts + f0) = c;
        }
        return;
    }

    u64 le_mask = ((1ull << lane) << 1) - 1ull;   // bits <= lane (lane 63 -> ~0)

    float4 offv = *(const float4*)(offsets + f0);  // f0 % 4 == 0, aligned
    float offa[QN] = {offv.x, offv.y, offv.z, offv.w};

    bool rank[QN]; u64 r1[QN];
    const float coef = (float)(64.0 / 44100.0);
#pragma unroll
    for (int q = 0; q < QN; ++q) {
        // exact: floor(x)>=1 <=> x>=1.0 ; min(63,floor(x))!=63 <=> x<63.0
        float xs_ = (s[q] - offa[q]) * coef;
        float xe_ = (e[q] - offa[q]) * coef;
        rank[q] = (xs_ >= 1.0f) && (xe_ < 63.0f);
        r1[q] = __ballot(rank[q]);
    }

    int startL[QN], endL[QN]; u64 span[QN];
#pragma unroll
    for (int q = 0; q < QN; ++q) {
        startL[q] = 63 - __builtin_clzll(gs[q] & le_mask);
        u64 above = gs[q] & ~le_mask;
        endL[q] = above ? (__builtin_ctzll(above) - 1) : 63;
        span[q] = (((1ull << endL[q]) << 1) - 1ull) & ~((1ull << startL[q]) - 1ull);
    }

    bool ismax[QN]; float cnt[QN];
#pragma unroll
    for (int q = 0; q < QN; ++q) {
        bool gmax = (r1[q] & span[q]) != 0ull;
        ismax[q] = (rank[q] == gmax);
        u64 im = __ballot(ismax[q]);
        cnt[q] = (float)__popcll(im & span[q]);   // >= 1 always
    }

    float xs[QN], xe[QN], ps[QN], pe[QN];
#pragma unroll
    for (int q = 0; q < QN; ++q) {
        xs[q] = ismax[q] ? s[q] : 0.0f;
        xe[q] = ismax[q] ? e[q] : 0.0f;
        ps[q] = xs[q]; pe[q] = xe[q];
    }
    scan_sum2_q(ps, pe);   // inclusive

#pragma unroll
    for (int q = 0; q < QN; ++q) {
        // exclusive prefix read at group start (startL==0 -> 0 naturally)
        float bs = __shfl(ps[q] - xs[q], startL[q], 64);
        float be = __shfl(pe[q] - xe[q], startL[q], 64);
        int gid = (int)__popcll(gs[q] & le_mask) - 1;
        if (lane == endL[q]) {
            float inv = __builtin_amdgcn_rcpf(cnt[q]);   // ~1ulp, threshold 4.5e5
            float2 r;
            r.x = (ps[q] - bs) * inv;
            r.y = (pe[q] - be) * inv;
            int frame = f0 + q;
            if (MODE == 0) {
                rows[(size_t)frame * NFRAG + gid] = r;
            } else {
                int b = frame >> 9;
                ((float2*)out)[(size_t)b * TROWS + offs[frame] + gid] = r;
            }
        }
    }
    if (MODE == 0 && lane == 0) {
        int4 c;
        c.x = (int)__popcll(gs[0]); c.y = (int)__popcll(gs[1]);
        c.z = (int)__popcll(gs[2]); c.w = (int)__popcll(gs[3]);
        *(int4*)(counts + f0) = c;
    }
}

// ---------- merged finish: per-block redundant batch scan + zero + compact ----------
// Grid: NB*64 blocks of 256. Block (b, r=bid&63): all blocks scan batch b's 512
// counts (2/thread, wave DPP scan + LDS wave-total combine); r<32 -> zero role
// (1024 rows each), r>=32 -> compact role (16 frames each).

template<bool COMPACT>
__global__ __launch_bounds__(256) void finish_kernel(const float2* __restrict__ rows,
                                                     const int* __restrict__ cnt,
                                                     float* __restrict__ out,
                                                     float* __restrict__ out_tail) {
    __shared__ int loff[NF + 1];
    __shared__ int wtot[4];
    int t = threadIdx.x;
    int lanel = t & 63, wv = t >> 6;
    int b = blockIdx.x >> 6, r = blockIdx.x & 63;

    int2 c01 = *(const int2*)(cnt + b * NF + t * 2);
    int sum2 = c01.x + c01.y;
    int inc = sum2;
    inc += dppi<0x111, 0xF, true>(inc, 0);
    inc += dppi<0x112, 0xF, true>(inc, 0);
    inc += dppi<0x114, 0xF, true>(inc, 0);
    inc += dppi<0x118, 0xF, true>(inc, 0);
    inc += dppi<0x142, 0xA, false>(inc, 0);
    inc += dppi<0x143, 0xC, false>(inc, 0);
    if (lanel == 63) wtot[wv] = inc;
    __syncthreads();
    int w0 = wtot[0], w1 = wtot[1], w2 = wtot[2], w3 = wtot[3];
    int base = (wv > 0 ? w0 : 0) + (wv > 1 ? w1 : 0) + (wv > 2 ? w2 : 0);
    int total = w0 + w1 + w2 + w3;
    int off0 = base + inc - sum2;                 // exclusive at count index 2t
    loff[t * 2] = off0;
    loff[t * 2 + 1] = off0 + c01.x;
    if (t == 255) loff[NF] = total;
    __syncthreads();

    if (r < 32) {
        int r0 = (r * 256 + t) * 4;
        float* p = out + ((size_t)b * TROWS + r0) * 2;
        if (r0 >= total) {
            *(float4*)p = make_float4(0.f, 0.f, 0.f, 0.f);
            *(float4*)(p + 4) = make_float4(0.f, 0.f, 0.f, 0.f);
        } else if (r0 + 4 > total) {
#pragma unroll
            for (int kk = 1; kk < 4; ++kk)
                if (r0 + kk >= total) *(float2*)(p + kk * 2) = make_float2(0.f, 0.f);
        }
        if (r == 0 && t == 0) out_tail[b] = (float)total;
    } else if (COMPACT) {
        int fl = (r - 32) * 16 + wv * 4;
#pragma unroll
        for (int q = 0; q < 4; ++q) {
            int fidx = fl + q;                    // wave-uniform -> LDS broadcast
            int o = loff[fidx];
            int G = loff[fidx + 1] - o;
            if (lanel < G) {
                ((float2*)out)[(size_t)b * TROWS + o + lanel] =
                    rows[((size_t)b * NF + fidx) * NFRAG + lanel];
            }
        }
    }
}

// ---------- per-batch exclusive scan (FALLBACK PATH ONLY) ----------

__global__ __launch_bounds__(64) void scan_kernel(const int* __restrict__ cnt,
                                                  int* __restrict__ offs) {
    int b = blockIdx.x, lanel = threadIdx.x;
    const int4* p = (const int4*)(cnt + b * NF);
    int4 v0 = p[lanel * 2], v1 = p[lanel * 2 + 1];
    int l[8] = {v0.x, v0.y, v0.z, v0.w, v1.x, v1.y, v1.z, v1.w};
    int pre[8], sum = 0;
#pragma unroll
    for (int kk = 0; kk < 8; ++kk) { pre[kk] = sum; sum += l[kk]; }
    int inc = sum;
    inc += dppi<0x111, 0xF, true>(inc, 0);
    inc += dppi<0x112, 0xF, true>(inc, 0);
    inc += dppi<0x114, 0xF, true>(inc, 0);
    inc += dppi<0x118, 0xF, true>(inc, 0);
    inc += dppi<0x142, 0xA, false>(inc, 0);
    inc += dppi<0x143, 0xC, false>(inc, 0);
    int base = inc - sum;
    int4 o0 = make_int4(base + pre[0], base + pre[1], base + pre[2], base + pre[3]);
    int4 o1 = make_int4(base + pre[4], base + pre[5], base + pre[6], base + pre[7]);
    int4* op = (int4*)(offs + b * NF);
    op[lanel * 2] = o0; op[lanel * 2 + 1] = o1;
}

extern "C" void kernel_launch(void* const* d_in, const int* in_sizes, int n_in,
                              void* d_out, int out_size, void* d_ws, size_t ws_size,
                              hipStream_t stream) {
    const float2* frags = (const float2*)d_in[0];   // [B,F,N,2] f32
    const float* offsets = (const float*)d_in[1];   // [B,F] f32
    float* out = (float*)d_out;

    int* counts = (int*)d_ws;
    int* offs = counts + NFRAMES;
    float2* rows = (float2*)((char*)d_ws + (size_t)2 * NFRAMES * sizeof(int));
    size_t small = (size_t)2 * NFRAMES * sizeof(int);
    size_t need = small + (size_t)NFRAMES * NFRAG * sizeof(float2);

    float* tail = out + (size_t)NB * TROWS * 2;

    if (ws_size >= need) {
        frag_kernel<0><<<NFRAMES / 16, 256, 0, stream>>>(frags, offsets, counts, nullptr, rows, nullptr);
        finish_kernel<true><<<NB * 64, 256, 0, stream>>>(rows, counts, out, tail);
    } else {
        frag_kernel<2><<<NFRAMES / 16, 256, 0, stream>>>(frags, offsets, counts, nullptr, nullptr, nullptr);
        scan_kernel<<<NB, 64, 0, stream>>>(counts, offs);
        finish_kernel<false><<<NB * 64, 256, 0, stream>>>(nullptr, counts, out, tail);
        frag_kernel<1><<<NFRAMES / 16, 256, 0, stream>>>(frags, offsets, counts, offs, nullptr, out);
    }
}